// Round 8
// baseline (82.235 us; speedup 1.0000x reference)
//
#include <hip/hip_runtime.h>
#include <hip/hip_bf16.h>
#include <hip/hip_cooperative_groups.h>

#define ACTIONS 64
#define EMB 32
#define DELTA 16
#define EPS 1e-5f

typedef float f32x4 __attribute__((ext_vector_type(4)));

// tanh(x) = 1 - 2/(1+exp(2x)); saturates correctly at +-1.
__device__ __forceinline__ float fast_tanhf(float x) {
    float e = __expf(2.0f * x);
    float r = __builtin_amdgcn_rcpf(1.0f + e);
    return 1.0f - 2.0f * r;
}

// Single fused cooperative kernel.
// Block = (rowtile, colgrp): 128 rows x 8 cols.
// Phase 1: stage x-slice (4 KB) + 33-knot sub-table (33 KB) to LDS; compute
//          per-column partial sum/sumsq of the slice from LDS; one writer per
//          partial slot -> deterministic, race-free.
// grid.sync() (1024 blocks = 4/CU x 256 CU co-resident: 39 KB LDS, 256 thr).
// Phase 2: reduce 128 rowtile-partials per column (fixed order), scale/shift,
//          then the R6-proven steady loop: ZERO global loads, nt stores
//          (in-order vmcnt never drains the store stream).
__global__ void __launch_bounds__(256) spline_fused_kernel(
        const f32x4* __restrict__ x4,
        const f32x4* __restrict__ emb4,
        float* __restrict__ sums,          // [nrowtiles*64]
        float* __restrict__ sqs,           // [nrowtiles*64]
        const float* __restrict__ bn_w,
        const float* __restrict__ bn_b,
        f32x4* __restrict__ out4,
        float inv_n, int nrt /* rowtiles/32 */) {
    __shared__ f32x4 tab4[33 * 64];     // 33 KB  [knot][ci][e4]
    __shared__ f32x4 xs4[256];          //  4 KB  128 rows x 8 cols
    __shared__ float scrA[32][8];       //  1 KB  reduction scratch (reused)
    __shared__ float scrB[32][8];       //  1 KB

    const int tid     = threadIdx.x;
    const int colgrp  = blockIdx.x & 7;
    const int rowtile = blockIdx.x >> 3;
    const int c0      = colgrp * 8;
    const int r0      = rowtile * 128;

    // ---- Phase 1: staging ----
    // x slice first (oldest in vmcnt queue -> retires first), then table.
    xs4[tid] = x4[(r0 + (tid >> 1)) * 16 + (c0 >> 2) + (tid & 1)];
    for (int u = tid; u < 33 * 64; u += 256) {
        tab4[u] = emb4[(u >> 6) * 512 + c0 * 8 + (u & 63)];
    }
    __syncthreads();

    // per-slice column stats from LDS
    const float* xs = (const float*)xs4;
    {
        const int ci = tid & 7, seg = tid >> 3;      // 32 segs x 4 rows
        float s = 0.f, q = 0.f;
        #pragma unroll
        for (int j = 0; j < 4; ++j) {
            const float v = xs[(seg * 4 + j) * 8 + ci];
            s += v;
            q = fmaf(v, v, q);
        }
        scrA[seg][ci] = s;
        scrB[seg][ci] = q;
    }
    __syncthreads();
    if (tid < 8) {
        float a = 0.f, b = 0.f;
        #pragma unroll
        for (int k = 0; k < 32; ++k) { a += scrA[k][tid]; b += scrB[k][tid]; }
        sums[rowtile * 64 + c0 + tid] = a;
        sqs [rowtile * 64 + c0 + tid] = b;
    }

    cooperative_groups::this_grid().sync();

    // ---- Phase 2: fold partials for this block's 8 columns ----
    {
        const int ci = tid & 7, chunk = tid >> 3;    // 32 chunks
        float s = 0.f, q = 0.f;
        for (int j = 0; j < nrt; ++j) {
            const int rt = chunk * nrt + j;
            s += sums[rt * 64 + c0 + ci];
            q += sqs [rt * 64 + c0 + ci];
        }
        scrA[chunk][ci] = s;
        scrB[chunk][ci] = q;
    }
    __syncthreads();

    const int ci      = (tid >> 3) & 7;   // column within group
    const int e4      = tid & 7;          // float4 within emb row
    const int row_off = tid >> 6;         // wave id 0..3
    float scale, shift;
    {
        float S = 0.f, Q = 0.f;
        #pragma unroll
        for (int k = 0; k < 32; ++k) { S += scrA[k][ci]; Q += scrB[k][ci]; }
        const float mean = S * inv_n;
        const float var  = fmaxf(Q * inv_n - mean * mean, 0.0f);
        scale = rsqrtf(var + EPS) * bn_w[c0 + ci];
        shift = bn_b[c0 + ci] - mean * scale;
    }

    // ---- steady store loop: zero global loads, nt stores ----
    #pragma unroll 4
    for (int it = 0; it < 32; ++it) {
        const int rl = it * 4 + row_off;             // local row
        const float xv = xs[rl * 8 + ci];            // LDS broadcast read

        float t = fast_tanhf(fmaf(xv, scale, shift));
        t = fminf(fmaxf(t, -1.0f + 1e-5f), 1.0f - 1e-5f);

        const float td  = t * (float)DELTA;
        const float xlf = floorf(td);
        const float xhf = floorf(td + 1.0f);         // mirror reference
        const int kl = (int)xlf + DELTA;             // 0..31
        const int kh = (int)xhf + DELTA;             // 1..32
        const float wl = xhf - td;
        const float wh = td - xlf;

        const f32x4 bl = tab4[kl * 64 + ci * 8 + e4];
        const f32x4 bh = tab4[kh * 64 + ci * 8 + e4];
        f32x4 o = bh * wh + bl * wl;
        // contiguous across the wave's 64 lanes -> 1 KiB segment
        __builtin_nontemporal_store(o, &out4[((r0 + rl) * ACTIONS + c0 + ci) * 8 + e4]);
    }
}

extern "C" void kernel_launch(void* const* d_in, const int* in_sizes, int n_in,
                              void* d_out, int out_size, void* d_ws, size_t ws_size,
                              hipStream_t stream) {
    const f32x4* x4   = (const f32x4*)d_in[0];
    const float* bn_w = (const float*)d_in[1];
    const float* bn_b = (const float*)d_in[2];
    const f32x4* emb4 = (const f32x4*)d_in[3];
    f32x4* out4       = (f32x4*)d_out;

    const int n = in_sizes[0] / ACTIONS;   // 16384
    const int nrowtiles = n / 128;         // 128
    const int blocks = 8 * nrowtiles;      // 1024 = 4/CU x 256 CU

    float* sums = (float*)d_ws;                    // nrowtiles*64 floats
    float* sqs  = (float*)d_ws + nrowtiles * 64;   // nrowtiles*64 floats

    float inv_n = 1.0f / (float)n;
    int   nrt   = nrowtiles / 32;          // 4

    void* args[] = { (void*)&x4, (void*)&emb4, (void*)&sums, (void*)&sqs,
                     (void*)&bn_w, (void*)&bn_b, (void*)&out4,
                     (void*)&inv_n, (void*)&nrt };
    hipLaunchCooperativeKernel((const void*)spline_fused_kernel,
                               dim3(blocks), dim3(256), args, 0, stream);
}

// Round 9
// 39.554 us; speedup vs baseline: 2.0791x; 2.0791x over previous
//
#include <hip/hip_runtime.h>
#include <hip/hip_bf16.h>

#define ACTIONS 64
#define EMB 32
#define DELTA 16
#define EPS 1e-5f

typedef float f32x4 __attribute__((ext_vector_type(4)));

// tanh(x) = 1 - 2/(1+exp(2x)); saturates correctly at +-1.
__device__ __forceinline__ float fast_tanhf(float x) {
    float e = __expf(2.0f * x);
    float r = __builtin_amdgcn_rcpf(1.0f + e);
    return 1.0f - 2.0f * r;
}

// ---------------- Kernel 1: per-column partial sums (float4) ----------------
// (R6-proven version, unchanged.)
__global__ void __launch_bounds__(256) bn_stats_kernel(const f32x4* __restrict__ x4,
                                                       float* __restrict__ partial,
                                                       int total4 /* n*64/4 */) {
    const int tid = threadIdx.x;
    f32x4 s = {0.f, 0.f, 0.f, 0.f};
    f32x4 q = {0.f, 0.f, 0.f, 0.f};
    const int stride = gridDim.x * 256;
    for (int i = blockIdx.x * 256 + tid; i < total4; i += stride) {
        f32x4 v = x4[i];
        s += v;
        q += v * v;
    }
    __shared__ f32x4 ssum[256];
    __shared__ f32x4 ssq[256];
    ssum[tid] = s;
    ssq[tid] = q;
    __syncthreads();
    if (tid < 16) {
        f32x4 a = ssum[tid];
        f32x4 b = ssq[tid];
        #pragma unroll
        for (int k = 1; k < 16; ++k) {
            a += ssum[tid + 16 * k];
            b += ssq[tid + 16 * k];
        }
        float* ps = partial + blockIdx.x * 128;
        #pragma unroll
        for (int j = 0; j < 4; ++j) {
            ps[4 * tid + j]      = a[j];
            ps[64 + 4 * tid + j] = b[j];
        }
    }
}

// ---------------- Kernel 2: main spline-embedding -------------------------
// THIS ROUND: block shrunk to 4 cols x 128 rows -> LDS 19.9 KB -> 8 blocks/CU
// = 32 waves/CU (8/SIMD, double R6's 4/SIMD). Theory: the R6 residual (~8 us
// over write-roofline) is a latency-bound store-issue rate: each iteration is
// a ~300-cy serial chain (LDS x-read -> tanh -> LDS gathers -> store) and 4
// waves/SIMD issue 1 KiB/75cy ~ marginal vs HBM 1 KiB/94cy. 8 waves/SIMD
// doubles the margin. Steady loop: ZERO global loads (R6-proven: in-order
// vmcnt would drain the nt-store stream), nt stores (R7: +1.3 us vs plain).
__global__ void __launch_bounds__(256, 8) spline_main_kernel(
        const f32x4* __restrict__ x4,
        const f32x4* __restrict__ emb4,
        const float* __restrict__ partial,
        const float* __restrict__ bn_w,
        const float* __restrict__ bn_b,
        f32x4* __restrict__ out4,
        float inv_n) {
    __shared__ f32x4 tab4[33 * 32];     // 16.9 KB  [knot][ci 0..3][e4]
    __shared__ f32x4 xs4[128];          //  2.0 KB  128 rows x 4 cols
    __shared__ float scr[2][32][4];     //  1.0 KB  [sum/sq][chunk][ci]

    const int tid     = threadIdx.x;
    const int colgrp  = blockIdx.x & 15;            // 16 groups of 4 cols
    const int rowtile = blockIdx.x >> 4;
    const int c0      = colgrp * 4;
    const int r0      = rowtile * 128;

    // ---- stage x slice (1 f4 per row; 128 threads) ----
    if (tid < 128) xs4[tid] = x4[(r0 + tid) * 16 + (c0 >> 2)];
    // ---- stage sub-table (contiguous 512 B per half-wave) ----
    for (int u = tid; u < 33 * 32; u += 256) {
        const int k = u >> 5, rest = u & 31;        // rest = ci*8+e4
        tab4[u] = emb4[k * 512 + c0 * 8 + rest];
    }
    // ---- fold stats partials for these 4 cols (fixed order -> determ.) ----
    {
        const int pci = tid & 3, half = (tid >> 2) & 1, chunk = tid >> 3;
        float s = 0.f;
        #pragma unroll
        for (int j = 0; j < 4; ++j)
            s += partial[(chunk * 4 + j) * 128 + half * 64 + c0 + pci];
        scr[half][chunk][pci] = s;
    }
    __syncthreads();

    const int e4      = tid & 7;          // float4 within emb row
    const int ci      = (tid >> 3) & 3;   // column within group
    const int r2      = (tid >> 5) & 1;   // row parity within wave
    const int row_off = tid >> 6;         // wave id 0..3
    float scale, shift;
    {
        float S = 0.f, Q = 0.f;
        #pragma unroll
        for (int k = 0; k < 32; ++k) { S += scr[0][k][ci]; Q += scr[1][k][ci]; }
        const float mean = S * inv_n;
        const float var  = fmaxf(Q * inv_n - mean * mean, 0.0f);
        scale = rsqrtf(var + EPS) * bn_w[c0 + ci];
        shift = bn_b[c0 + ci] - mean * scale;
    }

    // ---- steady store loop: zero global loads, nt stores ----
    // wave handles 2 rows/iter (r2); block 8 rows/iter; 16 iters for 128.
    const float* xs = (const float*)xs4;
    #pragma unroll 4
    for (int it = 0; it < 16; ++it) {
        const int rl = it * 8 + row_off * 2 + r2;    // local row
        const float xv = xs[rl * 4 + ci];            // LDS broadcast read

        float t = fast_tanhf(fmaf(xv, scale, shift));
        t = fminf(fmaxf(t, -1.0f + 1e-5f), 1.0f - 1e-5f);

        const float td  = t * (float)DELTA;
        const float xlf = floorf(td);
        const float xhf = floorf(td + 1.0f);         // mirror reference
        const int kl = (int)xlf + DELTA;             // 0..31
        const int kh = (int)xhf + DELTA;             // 1..32
        const float wl = xhf - td;
        const float wh = td - xlf;

        const f32x4 bl = tab4[kl * 32 + ci * 8 + e4];
        const f32x4 bh = tab4[kh * 32 + ci * 8 + e4];
        f32x4 o = bh * wh + bl * wl;
        // 32 lanes per row -> 512 B contiguous per half-wave
        __builtin_nontemporal_store(o, &out4[((r0 + rl) * ACTIONS + c0 + ci) * 8 + e4]);
    }
}

extern "C" void kernel_launch(void* const* d_in, const int* in_sizes, int n_in,
                              void* d_out, int out_size, void* d_ws, size_t ws_size,
                              hipStream_t stream) {
    const float* x    = (const float*)d_in[0];
    const float* bn_w = (const float*)d_in[1];
    const float* bn_b = (const float*)d_in[2];
    const float* emb  = (const float*)d_in[3];
    float* out        = (float*)d_out;

    const int n = in_sizes[0] / ACTIONS;   // 16384
    const int total = n * ACTIONS;

    float* partial = (float*)d_ws;         // 128 * 128 floats

    const int STATS_BLOCKS = 128;
    bn_stats_kernel<<<STATS_BLOCKS, 256, 0, stream>>>((const f32x4*)x, partial, total / 4);

    // 16 col-groups x (n/128) row-tiles = 2048 blocks (8/CU, 19.9 KB LDS)
    const int blocks = 16 * (n / 128);
    spline_main_kernel<<<blocks, 256, 0, stream>>>((const f32x4*)x, (const f32x4*)emb,
                                                   partial, bn_w, bn_b, (f32x4*)out,
                                                   1.0f / (float)n);
}

// Round 10
// 37.293 us; speedup vs baseline: 2.2051x; 1.0606x over previous
//
#include <hip/hip_runtime.h>
#include <hip/hip_bf16.h>

#define ACTIONS 64
#define EMB 32
#define DELTA 16
#define EPS 1e-5f

typedef float f32x4 __attribute__((ext_vector_type(4)));

// tanh(x) = 1 - 2/(1+exp(2x)); saturates correctly at +-1.
__device__ __forceinline__ float fast_tanhf(float x) {
    float e = __expf(2.0f * x);
    float r = __builtin_amdgcn_rcpf(1.0f + e);
    return 1.0f - 2.0f * r;
}

// ---------------- Kernel 1: per-column partial sums (float4) ----------------
// (R6-proven version, unchanged.)
__global__ void __launch_bounds__(256) bn_stats_kernel(const f32x4* __restrict__ x4,
                                                       float* __restrict__ partial,
                                                       int total4 /* n*64/4 */) {
    const int tid = threadIdx.x;
    f32x4 s = {0.f, 0.f, 0.f, 0.f};
    f32x4 q = {0.f, 0.f, 0.f, 0.f};
    const int stride = gridDim.x * 256;
    for (int i = blockIdx.x * 256 + tid; i < total4; i += stride) {
        f32x4 v = x4[i];
        s += v;
        q += v * v;
    }
    __shared__ f32x4 ssum[256];
    __shared__ f32x4 ssq[256];
    ssum[tid] = s;
    ssq[tid] = q;
    __syncthreads();
    if (tid < 16) {
        f32x4 a = ssum[tid];
        f32x4 b = ssq[tid];
        #pragma unroll
        for (int k = 1; k < 16; ++k) {
            a += ssum[tid + 16 * k];
            b += ssq[tid + 16 * k];
        }
        float* ps = partial + blockIdx.x * 128;
        #pragma unroll
        for (int j = 0; j < 4; ++j) {
            ps[4 * tid + j]      = a[j];
            ps[64 + 4 * tid + j] = b[j];
        }
    }
}

// ---------------- Kernel 2: main spline-embedding -------------------------
// R6 geometry: block = 8 cols x 128 rows, LDS 38.4 KB -> 4 blocks/CU,
// zero global loads in steady loop (R6: in-order vmcnt would drain the
// store stream), nt stores (R7: +1.3 us vs plain).
// THIS ROUND (single variable): split the steady loop into chunks of 8 rows —
// phase A precomputes {gather offset, wl, wh} for 8 rows into registers
// (x-read + tanh moved OFF the store path), phase B bursts 8x
// {2 LDS gathers + fma + nt store} back-to-back.
__global__ void __launch_bounds__(256) spline_main_kernel(
        const f32x4* __restrict__ x4,
        const f32x4* __restrict__ emb4,
        const float* __restrict__ partial,
        const float* __restrict__ bn_w,
        const float* __restrict__ bn_b,
        f32x4* __restrict__ out4,
        float inv_n) {
    __shared__ f32x4 tab4[33 * 64];     // 33 KB  [knot][ci][e4]
    __shared__ f32x4 xs4[256];          //  4 KB  128 rows x 8 cols
    __shared__ float psum[2][8][16];    //  1 KB  [half][ci][chunk]

    const int tid     = threadIdx.x;
    const int colgrp  = blockIdx.x & 7;
    const int rowtile = blockIdx.x >> 3;
    const int c0      = colgrp * 8;
    const int r0      = rowtile * 128;

    // stage x slice first (oldest vmcnt entries retire first), then table
    xs4[tid] = x4[(r0 + (tid >> 1)) * 16 + (c0 >> 2) + (tid & 1)];
    for (int u = tid; u < 33 * 64; u += 256) {
        tab4[u] = emb4[(u >> 6) * 512 + c0 * 8 + (u & 63)];
    }
    // fold stats partials for these 8 cols (fixed order -> deterministic)
    {
        const int pci = tid & 7, half = (tid >> 3) & 1, chunk = tid >> 4;
        float s = 0.f;
        #pragma unroll
        for (int k = 0; k < 8; ++k)
            s += partial[(chunk * 8 + k) * 128 + half * 64 + c0 + pci];
        psum[half][pci][chunk] = s;
    }
    __syncthreads();

    const int ci      = (tid >> 3) & 7;   // column within group
    const int e4      = tid & 7;          // float4 within emb row
    const int row_off = tid >> 6;         // wave id 0..3
    float scale, shift;
    {
        float S = 0.f, Q = 0.f;
        #pragma unroll
        for (int k = 0; k < 16; ++k) { S += psum[0][ci][k]; Q += psum[1][ci][k]; }
        const float mean = S * inv_n;
        const float var  = fmaxf(Q * inv_n - mean * mean, 0.0f);
        scale = rsqrtf(var + EPS) * bn_w[c0 + ci];
        shift = bn_b[c0 + ci] - mean * scale;
    }

    // ---- steady store loop: 4 chunks x 8 rows per wave ----
    const float* xs = (const float*)xs4;
    const char* tabB = (const char*)tab4;
    const int lane_off = (ci * 8 + e4) * 16;    // byte offset within a knot row

    for (int c = 0; c < 4; ++c) {
        // phase A: precompute params for 8 rows (off the store path)
        int   offl[8];
        float wl[8], wh[8];
        #pragma unroll
        for (int j = 0; j < 8; ++j) {
            const int rl = c * 32 + j * 4 + row_off;     // local row
            const float xv = xs[rl * 8 + ci];            // LDS broadcast read
            float t = fast_tanhf(fmaf(xv, scale, shift));
            t = fminf(fmaxf(t, -1.0f + 1e-5f), 1.0f - 1e-5f);
            const float td  = t * (float)DELTA;
            const float xlf = floorf(td);
            const float xhf = floorf(td + 1.0f);         // mirror reference
            const int kl = (int)xlf + DELTA;             // 0..31 (kh = kl+1)
            offl[j] = kl * 1024 + lane_off;              // 64 f4 * 16 B per knot
            wl[j] = xhf - td;
            wh[j] = td - xlf;
        }
        // phase B: tight gather+store burst (8 stores back-to-back)
        #pragma unroll
        for (int j = 0; j < 8; ++j) {
            const int rl = c * 32 + j * 4 + row_off;
            const f32x4 bl = *reinterpret_cast<const f32x4*>(tabB + offl[j]);
            const f32x4 bh = *reinterpret_cast<const f32x4*>(tabB + offl[j] + 1024);
            f32x4 o = bh * wh[j] + bl * wl[j];
            // contiguous across the wave's 64 lanes -> 1 KiB segment
            __builtin_nontemporal_store(o, &out4[((r0 + rl) * ACTIONS + c0 + ci) * 8 + e4]);
        }
    }
}

extern "C" void kernel_launch(void* const* d_in, const int* in_sizes, int n_in,
                              void* d_out, int out_size, void* d_ws, size_t ws_size,
                              hipStream_t stream) {
    const float* x    = (const float*)d_in[0];
    const float* bn_w = (const float*)d_in[1];
    const float* bn_b = (const float*)d_in[2];
    const float* emb  = (const float*)d_in[3];
    float* out        = (float*)d_out;

    const int n = in_sizes[0] / ACTIONS;   // 16384
    const int total = n * ACTIONS;

    float* partial = (float*)d_ws;         // 128 * 128 floats

    const int STATS_BLOCKS = 128;
    bn_stats_kernel<<<STATS_BLOCKS, 256, 0, stream>>>((const f32x4*)x, partial, total / 4);

    // 8 col-groups x (n/128) row-tiles = 1024 blocks (4/CU, 38.4 KB LDS)
    const int blocks = 8 * (n / 128);
    spline_main_kernel<<<blocks, 256, 0, stream>>>((const f32x4*)x, (const f32x4*)emb,
                                                   partial, bn_w, bn_b, (f32x4*)out,
                                                   1.0f / (float)n);
}